// Round 9
// baseline (131.558 us; speedup 1.0000x reference)
//
#include <hip/hip_runtime.h>
#include <hip/hip_bf16.h>

// Variable_Attention: out = softmax(relu((x@WQ)(x@WK)^T)/sqrt(128), axis=-1)
// B=16, N=2048, T=96, D=128. fp32 in/out.
//
// QK^T/sqrt(d) = x Ms x^T with Ms = (WQ WK^T)/sqrt(d) (96x96, exact fp32):
//   k_m    : Ms^T -> fp16 hi/lo split
//   k_fuse : reads x once (LDS-staged); emits y = x@Ms (fp32) and Bp = x
//            split fp16 hi/lo in MFMA B-fragment stream order (1KB frags)
//   k_attn : S = y@x^T (K=96, 3-term split-fp16 MFMA) fused relu/softmax.
//            BM=32/block, 512 thr. Asm-pipelined B loads (depth-2, vmcnt(6)).
//            R8: LDS-transpose + row-contiguous 1KB burst stores (+32us).
//            R9: burst stores are NONTEMPORAL (keep 256MB write stream from
//            evicting Bp out of per-XCD L2 - the R4 lesson, now combined
//            with full-line bursts) + transpose pad 1032->1028 floats
//            (4-way -> free 2-way bank aliasing on transpose writes).
// Workspace: ~38 MB.

typedef _Float16 f16;
typedef _Float16 half8 __attribute__((ext_vector_type(8)));
typedef float float4v __attribute__((ext_vector_type(4)));

#define B_ 16
#define N_ 2048
#define T_ 96
#define D_ 128

static __device__ __forceinline__ half8 as_h8(float4v v) {
    union { float4v f; half8 h; } u; u.f = v; return u.h;
}

// ---------------------------------------------------------------------------
// k_m: Ms[t][t2] = (sum_d WQ[t,d]*WK[t2,d])/sqrt(128), transposed + split.
// ---------------------------------------------------------------------------
__global__ void k_m(const float* __restrict__ WQ, const float* __restrict__ WK,
                    f16* __restrict__ mth, f16* __restrict__ mtl) {
    int i = blockIdx.x * 256 + threadIdx.x;
    if (i >= T_ * T_) return;
    int t = i / T_, t2 = i % T_;
    const float4v* q = (const float4v*)(WQ + (size_t)t * D_);
    const float4v* k = (const float4v*)(WK + (size_t)t2 * D_);
    float s = 0.0f;
#pragma unroll
    for (int d = 0; d < D_ / 4; ++d) {
        float4v a = q[d], b = k[d];
        s += a[0] * b[0] + a[1] * b[1] + a[2] * b[2] + a[3] * b[3];
    }
    s *= 0.088388347648318447f;   // 1/sqrt(128) folded in (exact fp32 here)
    f16 h = (f16)s;
    mth[t2 * T_ + t] = h;
    mtl[t2 * T_ + t] = (f16)(s - (float)h);
}

// ---------------------------------------------------------------------------
// k_fuse: per block, 128 x-rows staged in LDS; (a) y = x@Ms (wave owns 32
// rows), (b) Bp pack (wave owns 2 col-tiles): frag[gct][ks][hl] = 1KB.
// ---------------------------------------------------------------------------
__global__ __launch_bounds__(256) void k_fuse(
        const float* __restrict__ x,
        const f16* __restrict__ mth, const f16* __restrict__ mtl,
        float* __restrict__ y, f16* __restrict__ bp) {
    __shared__ float xs[128][100];   // 51.2 KB, +4 pad -> conflict-free reads

    const int tid  = (int)threadIdx.x;
    const int lane = tid & 63;
    const int wave = tid >> 6;
    const int lr = lane & 15;
    const int lk = lane >> 4;
    const size_t rbase = (size_t)blockIdx.x * 128;

    // ---- fill LDS: 128 rows x 96 floats, fully coalesced float4 ----
    const float4v* xg = (const float4v*)(x + rbase * T_);
#pragma unroll
    for (int i = 0; i < 12; ++i) {
        int j = i * 256 + tid;           // 3072 float4 chunks
        int row = j / 24, c4 = j % 24;
        float4v v = xg[j];
        *(float4v*)&xs[row][c4 * 4] = v;
    }
    __syncthreads();

    // ---- y-GEMM: wave owns rows [wave*32, +32) ----
    half8 aH[2][3], aL[2][3];
#pragma unroll
    for (int mt = 0; mt < 2; ++mt)
#pragma unroll
        for (int ks = 0; ks < 3; ++ks) {
            const float* p = &xs[wave * 32 + mt * 16 + lr][ks * 32 + lk * 8];
            float4v v0 = *(const float4v*)p;
            float4v v1 = *(const float4v*)(p + 4);
            half8 h, l;
#pragma unroll
            for (int j = 0; j < 4; ++j) {
                f16 h0 = (f16)v0[j]; h[j] = h0; l[j] = (f16)(v0[j] - (float)h0);
                f16 h1 = (f16)v1[j]; h[4 + j] = h1; l[4 + j] = (f16)(v1[j] - (float)h1);
            }
            aH[mt][ks] = h;
            aL[mt][ks] = l;
        }

    float4v acc[2][6];
#pragma unroll
    for (int mt = 0; mt < 2; ++mt)
#pragma unroll
        for (int nt = 0; nt < 6; ++nt) {
            float4v z = {0.f, 0.f, 0.f, 0.f};
            acc[mt][nt] = z;
        }

#pragma unroll
    for (int nt = 0; nt < 6; ++nt) {
        half8 bH[3], bL[3];
#pragma unroll
        for (int ks = 0; ks < 3; ++ks) {
            size_t off = (size_t)(nt * 16 + lr) * T_ + ks * 32 + lk * 8;
            bH[ks] = *(const half8*)(mth + off);
            bL[ks] = *(const half8*)(mtl + off);
        }
#pragma unroll
        for (int ks = 0; ks < 3; ++ks)
#pragma unroll
            for (int mt = 0; mt < 2; ++mt) {
                acc[mt][nt] = __builtin_amdgcn_mfma_f32_16x16x32_f16(aH[mt][ks], bH[ks], acc[mt][nt], 0, 0, 0);
                acc[mt][nt] = __builtin_amdgcn_mfma_f32_16x16x32_f16(aH[mt][ks], bL[ks], acc[mt][nt], 0, 0, 0);
                acc[mt][nt] = __builtin_amdgcn_mfma_f32_16x16x32_f16(aL[mt][ks], bH[ks], acc[mt][nt], 0, 0, 0);
            }
    }

#pragma unroll
    for (int mt = 0; mt < 2; ++mt)
#pragma unroll
        for (int nt = 0; nt < 6; ++nt)
#pragma unroll
            for (int r = 0; r < 4; ++r)
                y[(rbase + wave * 32 + mt * 16 + lk * 4 + r) * T_ + nt * 16 + lr] = acc[mt][nt][r];

    // ---- Bp pack: wave owns col-tiles wave*2 + {0,1} of this block ----
#pragma unroll
    for (int ctl = 0; ctl < 2; ++ctl) {
        const int lct = wave * 2 + ctl;                 // 0..7
        const size_t gct = rbase / 16 + lct;            // global col-tile
#pragma unroll
        for (int ks = 0; ks < 3; ++ks) {
            const float* p = &xs[lct * 16 + lr][ks * 32 + lk * 8];
            float4v v0 = *(const float4v*)p;
            float4v v1 = *(const float4v*)(p + 4);
            half8 h, l;
#pragma unroll
            for (int j = 0; j < 4; ++j) {
                f16 h0 = (f16)v0[j]; h[j] = h0; l[j] = (f16)(v0[j] - (float)h0);
                f16 h1 = (f16)v1[j]; h[4 + j] = h1; l[4 + j] = (f16)(v1[j] - (float)h1);
            }
            f16* ob = bp + ((gct * 3 + ks) * 2) * 512 + (size_t)lane * 8;
            *(half8*)ob = h;
            *(half8*)(ob + 512) = l;
        }
    }
}

// ---------------------------------------------------------------------------
// k_attn: S = y @ x^T fused relu/softmax. 32 rows x 2048 cols per block.
// Wave w owns cols [w*128,+128) of group0 (cols 0-1023) and [1024+w*128,+128)
// of group1. Epilogue: per group, LDS transpose (32x1028 pad) then each wave
// writes 4 FULL rows as sequential 1KB NONTEMPORAL dwordx4 bursts.
// ---------------------------------------------------------------------------
__global__ __launch_bounds__(512, 2) void k_attn(
        const f16* __restrict__ bp, const float* __restrict__ y,
        float* __restrict__ out) {
    __shared__ float ot[32][1028];    // 131.6 KB transpose buffer (pad=2-way)
    __shared__ float red[8][32];
    __shared__ float stat[32];

    const int tid  = (int)threadIdx.x;
    const int lane = tid & 63;
    const int wave = tid >> 6;
    const int lr = lane & 15;
    const int lk = lane >> 4;

    // XCD-aware bijective swizzle (1024 blocks)
    const int lb   = ((int)blockIdx.x & 7) * 128 + ((int)blockIdx.x >> 3);
    const int b    = lb >> 6;
    const int row0 = (lb & 63) << 5;          // 32 rows per block
    const size_t obase = (size_t)b * N_ * N_;

    // ---- A: y rows (fp32, pre-scaled) split on the fly (read-once, NT) ----
    half8 aH[2][3], aL[2][3];
#pragma unroll
    for (int mt = 0; mt < 2; ++mt)
#pragma unroll
        for (int ks = 0; ks < 3; ++ks) {
            const float* p = y + ((size_t)b * N_ + row0 + mt * 16 + lr) * T_ + ks * 32 + lk * 8;
            float4v v0 = __builtin_nontemporal_load((const float4v*)p);
            float4v v1 = __builtin_nontemporal_load((const float4v*)p + 1);
            half8 h, l;
#pragma unroll
            for (int j = 0; j < 4; ++j) {
                f16 h0 = (f16)v0[j]; h[j] = h0; l[j] = (f16)(v0[j] - (float)h0);
                f16 h1 = (f16)v1[j]; h[4 + j] = h1; l[4 + j] = (f16)(v1[j] - (float)h1);
            }
            aH[mt][ks] = h;
            aL[mt][ks] = l;
        }

    float4v acc[2][16];
#pragma unroll
    for (int mt = 0; mt < 2; ++mt)
#pragma unroll
        for (int c = 0; c < 16; ++c) {
            float4v z = {0.f, 0.f, 0.f, 0.f};
            acc[mt][c] = z;
        }

    // col-tile index for loop index c (group-contiguous mapping):
    //   c<8 : tile = wave*8 + c         (cols wave*128 + c*16 in [0,1024))
    //   c>=8: tile = 64 + wave*8 + c-8  (cols 1024 + wave*128 + (c-8)*16)
#define TIDX(c) (((c) & 8 ? 64 : 0) + (wave << 3) + ((c) & 7))

    const f16* gb = bp + ((size_t)b * 128 * 6) * 512 + (size_t)lane * 8;

    float4v b0[6], b1[6];
#define ISSUE(ti, dst)                                                        \
    {                                                                         \
        _Pragma("unroll")                                                     \
        for (int f = 0; f < 6; ++f) {                                         \
            const f16* g = gb + (size_t)(ti) * 3072 + f * 512;                \
            asm volatile("global_load_dwordx4 %0, %1, off"                    \
                         : "=&v"(dst[f]) : "v"(g));                           \
        }                                                                     \
    }

    ISSUE(TIDX(0), b0);
    ISSUE(TIDX(1), b1);
    __builtin_amdgcn_sched_barrier(0);

#pragma unroll
    for (int c = 0; c < 16; ++c) {
        if (c < 15) asm volatile("s_waitcnt vmcnt(6)" ::: "memory");
        else        asm volatile("s_waitcnt vmcnt(0)" ::: "memory");
        __builtin_amdgcn_sched_barrier(0);

        __builtin_amdgcn_s_setprio(1);
        if ((c & 1) == 0) {
#pragma unroll
            for (int ks = 0; ks < 3; ++ks) {
                acc[0][c] = __builtin_amdgcn_mfma_f32_16x16x32_f16(aH[0][ks], as_h8(b0[ks * 2]),     acc[0][c], 0, 0, 0);
                acc[1][c] = __builtin_amdgcn_mfma_f32_16x16x32_f16(aH[1][ks], as_h8(b0[ks * 2]),     acc[1][c], 0, 0, 0);
                acc[0][c] = __builtin_amdgcn_mfma_f32_16x16x32_f16(aH[0][ks], as_h8(b0[ks * 2 + 1]), acc[0][c], 0, 0, 0);
                acc[1][c] = __builtin_amdgcn_mfma_f32_16x16x32_f16(aH[1][ks], as_h8(b0[ks * 2 + 1]), acc[1][c], 0, 0, 0);
                acc[0][c] = __builtin_amdgcn_mfma_f32_16x16x32_f16(aL[0][ks], as_h8(b0[ks * 2]),     acc[0][c], 0, 0, 0);
                acc[1][c] = __builtin_amdgcn_mfma_f32_16x16x32_f16(aL[1][ks], as_h8(b0[ks * 2]),     acc[1][c], 0, 0, 0);
            }
            __builtin_amdgcn_s_setprio(0);
            __builtin_amdgcn_sched_barrier(0);
            if (c + 2 < 16) ISSUE(TIDX(c + 2), b0);
        } else {
#pragma unroll
            for (int ks = 0; ks < 3; ++ks) {
                acc[0][c] = __builtin_amdgcn_mfma_f32_16x16x32_f16(aH[0][ks], as_h8(b1[ks * 2]),     acc[0][c], 0, 0, 0);
                acc[1][c] = __builtin_amdgcn_mfma_f32_16x16x32_f16(aH[1][ks], as_h8(b1[ks * 2]),     acc[1][c], 0, 0, 0);
                acc[0][c] = __builtin_amdgcn_mfma_f32_16x16x32_f16(aH[0][ks], as_h8(b1[ks * 2 + 1]), acc[0][c], 0, 0, 0);
                acc[1][c] = __builtin_amdgcn_mfma_f32_16x16x32_f16(aH[1][ks], as_h8(b1[ks * 2 + 1]), acc[1][c], 0, 0, 0);
                acc[0][c] = __builtin_amdgcn_mfma_f32_16x16x32_f16(aL[0][ks], as_h8(b1[ks * 2]),     acc[0][c], 0, 0, 0);
                acc[1][c] = __builtin_amdgcn_mfma_f32_16x16x32_f16(aL[1][ks], as_h8(b1[ks * 2]),     acc[1][c], 0, 0, 0);
            }
            __builtin_amdgcn_s_setprio(0);
            __builtin_amdgcn_sched_barrier(0);
            if (c + 2 < 16) ISSUE(TIDX(c + 2), b1);
        }
        __builtin_amdgcn_sched_barrier(0);
    }
#undef ISSUE
#undef TIDX

    // ---- relu (scale folded into Ms), row max ----
    float rmax[2][4];
#pragma unroll
    for (int mt = 0; mt < 2; ++mt)
#pragma unroll
        for (int r = 0; r < 4; ++r) rmax[mt][r] = 0.0f;
#pragma unroll
    for (int mt = 0; mt < 2; ++mt)
#pragma unroll
        for (int c = 0; c < 16; ++c)
#pragma unroll
            for (int r = 0; r < 4; ++r) {
                float v = fmaxf(acc[mt][c][r], 0.0f);
                acc[mt][c][r] = v;
                rmax[mt][r] = fmaxf(rmax[mt][r], v);
            }
#pragma unroll
    for (int mt = 0; mt < 2; ++mt)
#pragma unroll
        for (int r = 0; r < 4; ++r) {
            float m = rmax[mt][r];
            m = fmaxf(m, __shfl_xor(m, 1));
            m = fmaxf(m, __shfl_xor(m, 2));
            m = fmaxf(m, __shfl_xor(m, 4));
            m = fmaxf(m, __shfl_xor(m, 8));
            rmax[mt][r] = m;
        }
    if (lr == 0) {
#pragma unroll
        for (int mt = 0; mt < 2; ++mt)
#pragma unroll
            for (int r = 0; r < 4; ++r)
                red[wave][mt * 16 + lk * 4 + r] = rmax[mt][r];
    }
    __syncthreads();
    if (tid < 32) {
        float m = red[0][tid];
#pragma unroll
        for (int w = 1; w < 8; ++w) m = fmaxf(m, red[w][tid]);
        stat[tid] = m;
    }
    __syncthreads();

    float rowm[2][4], rsum[2][4];
#pragma unroll
    for (int mt = 0; mt < 2; ++mt)
#pragma unroll
        for (int r = 0; r < 4; ++r) {
            rowm[mt][r] = stat[mt * 16 + lk * 4 + r];
            rsum[mt][r] = 0.0f;
        }

    // ---- exp, row sum ----
#pragma unroll
    for (int mt = 0; mt < 2; ++mt)
#pragma unroll
        for (int c = 0; c < 16; ++c)
#pragma unroll
            for (int r = 0; r < 4; ++r) {
                float e = __expf(acc[mt][c][r] - rowm[mt][r]);
                acc[mt][c][r] = e;
                rsum[mt][r] += e;
            }
#pragma unroll
    for (int mt = 0; mt < 2; ++mt)
#pragma unroll
        for (int r = 0; r < 4; ++r) {
            float s = rsum[mt][r];
            s += __shfl_xor(s, 1);
            s += __shfl_xor(s, 2);
            s += __shfl_xor(s, 4);
            s += __shfl_xor(s, 8);
            rsum[mt][r] = s;
        }
    __syncthreads();
    if (lr == 0) {
#pragma unroll
        for (int mt = 0; mt < 2; ++mt)
#pragma unroll
            for (int r = 0; r < 4; ++r)
                red[wave][mt * 16 + lk * 4 + r] = rsum[mt][r];
    }
    __syncthreads();
    if (tid < 32) {
        float s = 0.0f;
#pragma unroll
        for (int w = 0; w < 8; ++w) s += red[w][tid];
        stat[tid] = s;
    }
    __syncthreads();

    float inv[2][4];
#pragma unroll
    for (int mt = 0; mt < 2; ++mt)
#pragma unroll
        for (int r = 0; r < 4; ++r)
            inv[mt][r] = 1.0f / stat[mt * 16 + lk * 4 + r];

    // ---- normalize + LDS transpose + NONTEMPORAL row-burst stores ----
#pragma unroll
    for (int g = 0; g < 2; ++g) {
        if (g) __syncthreads();   // protect ot reuse
#pragma unroll
        for (int cc = 0; cc < 8; ++cc) {
            const int c = g * 8 + cc;
#pragma unroll
            for (int mt = 0; mt < 2; ++mt)
#pragma unroll
                for (int r = 0; r < 4; ++r)
                    ot[mt * 16 + lk * 4 + r][(wave << 7) + cc * 16 + lr] =
                        acc[mt][c][r] * inv[mt][r];
        }
        __syncthreads();
        // each wave writes 4 full rows of this 1024-col group: 1KB NT bursts
#pragma unroll
        for (int rr = 0; rr < 4; ++rr) {
            const int row = (wave << 2) + rr;
            float* dstp = out + obase + (size_t)(row0 + row) * N_ + g * 1024;
#pragma unroll
            for (int i = 0; i < 4; ++i) {
                float4v v = *(const float4v*)&ot[row][i * 256 + lane * 4];
                __builtin_nontemporal_store(v, (float4v*)(dstp + i * 256 + lane * 4));
            }
        }
    }
}

// ---------------------------------------------------------------------------
extern "C" void kernel_launch(void* const* d_in, const int* in_sizes, int n_in,
                              void* d_out, int out_size, void* d_ws, size_t ws_size,
                              hipStream_t stream) {
    const float* x  = (const float*)d_in[0];
    const float* WQ = (const float*)d_in[1];
    const float* WK = (const float*)d_in[2];
    float* out = (float*)d_out;

    char* ws = (char*)d_ws;
    size_t off = 0;
    auto carve = [&](size_t bytes) -> char* {
        char* p = ws + off;
        off += (bytes + 255) & ~(size_t)255;
        return p;
    };
    f16*   mth = (f16*)carve((size_t)T_ * T_ * 2);
    f16*   mtl = (f16*)carve((size_t)T_ * T_ * 2);
    f16*   bpk = (f16*)carve((size_t)B_ * N_ * T_ * 2 * 2);   // 25.2 MB
    float* yw  = (float*)carve((size_t)B_ * N_ * T_ * 4);     // 12.6 MB
    (void)ws_size; (void)in_sizes; (void)n_in; (void)out_size;

    k_m<<<(T_ * T_ + 255) / 256, 256, 0, stream>>>(WQ, WK, mth, mtl);
    k_fuse<<<(B_ * N_) / 128, 256, 0, stream>>>(x, mth, mtl, yw, bpk);
    k_attn<<<B_ * (N_ / 32), 512, 0, stream>>>(bpk, yw, out);
}

// Round 13
// 127.283 us; speedup vs baseline: 1.0336x; 1.0336x over previous
//
#include <hip/hip_runtime.h>
#include <hip/hip_bf16.h>

// Variable_Attention: out = softmax(relu((x@WQ)(x@WK)^T)/sqrt(128), axis=-1)
// B=16, N=2048, T=96, D=128. fp32 in/out.
//
// QK^T/sqrt(d) = x Ms x^T with Ms = (WQ WK^T)/sqrt(d) (96x96, exact fp32):
//   k_m    : Ms^T -> fp16 hi/lo split
//   k_fuse : reads x once (LDS-staged); emits y = x@Ms (fp32) and Bp = x
//            split fp16 hi/lo in MFMA B-fragment stream order (1KB frags)
//   k_attn : PERSISTENT (grid=256, 1 block/CU, 4 row-blocks per block),
//            it-loop FULLY UNROLLED. R11 failed because in-flight asm-load
//            destinations (b0/b1) were loop-carried across a backedge ->
//            allocator PHI copies/spills read registers before the loads
//            landed. Unrolling makes every ISSUE->waitcnt window straight-
//            line (the regime R8 proved correct at this pressure).
//            Asm-pipelined B (depth-2, vmcnt(6)); next row-block's A + first
//            B sets prefetched during the epilogue; LDS-transpose + plain
//            1KB burst stores (R9: NT stores regress).
//            (R12 was an infra failure before execution - resubmitted as-is.)
// Workspace: ~38 MB.

typedef _Float16 f16;
typedef _Float16 half8 __attribute__((ext_vector_type(8)));
typedef float float4v __attribute__((ext_vector_type(4)));

#define B_ 16
#define N_ 2048
#define T_ 96
#define D_ 128

static __device__ __forceinline__ half8 as_h8(float4v v) {
    union { float4v f; half8 h; } u; u.f = v; return u.h;
}

// ---------------------------------------------------------------------------
// k_m: Ms[t][t2] = (sum_d WQ[t,d]*WK[t2,d])/sqrt(128), transposed + split.
// ---------------------------------------------------------------------------
__global__ void k_m(const float* __restrict__ WQ, const float* __restrict__ WK,
                    f16* __restrict__ mth, f16* __restrict__ mtl) {
    int i = blockIdx.x * 256 + threadIdx.x;
    if (i >= T_ * T_) return;
    int t = i / T_, t2 = i % T_;
    const float4v* q = (const float4v*)(WQ + (size_t)t * D_);
    const float4v* k = (const float4v*)(WK + (size_t)t2 * D_);
    float s = 0.0f;
#pragma unroll
    for (int d = 0; d < D_ / 4; ++d) {
        float4v a = q[d], b = k[d];
        s += a[0] * b[0] + a[1] * b[1] + a[2] * b[2] + a[3] * b[3];
    }
    s *= 0.088388347648318447f;   // 1/sqrt(128) folded in (exact fp32 here)
    f16 h = (f16)s;
    mth[t2 * T_ + t] = h;
    mtl[t2 * T_ + t] = (f16)(s - (float)h);
}

// ---------------------------------------------------------------------------
// k_fuse: per block, 128 x-rows staged in LDS; (a) y = x@Ms (wave owns 32
// rows), (b) Bp pack (wave owns 2 col-tiles): frag[gct][ks][hl] = 1KB.
// ---------------------------------------------------------------------------
__global__ __launch_bounds__(256) void k_fuse(
        const float* __restrict__ x,
        const f16* __restrict__ mth, const f16* __restrict__ mtl,
        float* __restrict__ y, f16* __restrict__ bp) {
    __shared__ float xs[128][100];   // 51.2 KB, +4 pad -> conflict-free reads

    const int tid  = (int)threadIdx.x;
    const int lane = tid & 63;
    const int wave = tid >> 6;
    const int lr = lane & 15;
    const int lk = lane >> 4;
    const size_t rbase = (size_t)blockIdx.x * 128;

    // ---- fill LDS: 128 rows x 96 floats, fully coalesced float4 ----
    const float4v* xg = (const float4v*)(x + rbase * T_);
#pragma unroll
    for (int i = 0; i < 12; ++i) {
        int j = i * 256 + tid;           // 3072 float4 chunks
        int row = j / 24, c4 = j % 24;
        float4v v = xg[j];
        *(float4v*)&xs[row][c4 * 4] = v;
    }
    __syncthreads();

    // ---- y-GEMM: wave owns rows [wave*32, +32) ----
    half8 aH[2][3], aL[2][3];
#pragma unroll
    for (int mt = 0; mt < 2; ++mt)
#pragma unroll
        for (int ks = 0; ks < 3; ++ks) {
            const float* p = &xs[wave * 32 + mt * 16 + lr][ks * 32 + lk * 8];
            float4v v0 = *(const float4v*)p;
            float4v v1 = *(const float4v*)(p + 4);
            half8 h, l;
#pragma unroll
            for (int j = 0; j < 4; ++j) {
                f16 h0 = (f16)v0[j]; h[j] = h0; l[j] = (f16)(v0[j] - (float)h0);
                f16 h1 = (f16)v1[j]; h[4 + j] = h1; l[4 + j] = (f16)(v1[j] - (float)h1);
            }
            aH[mt][ks] = h;
            aL[mt][ks] = l;
        }

    float4v acc[2][6];
#pragma unroll
    for (int mt = 0; mt < 2; ++mt)
#pragma unroll
        for (int nt = 0; nt < 6; ++nt) {
            float4v z = {0.f, 0.f, 0.f, 0.f};
            acc[mt][nt] = z;
        }

#pragma unroll
    for (int nt = 0; nt < 6; ++nt) {
        half8 bH[3], bL[3];
#pragma unroll
        for (int ks = 0; ks < 3; ++ks) {
            size_t off = (size_t)(nt * 16 + lr) * T_ + ks * 32 + lk * 8;
            bH[ks] = *(const half8*)(mth + off);
            bL[ks] = *(const half8*)(mtl + off);
        }
#pragma unroll
        for (int ks = 0; ks < 3; ++ks)
#pragma unroll
            for (int mt = 0; mt < 2; ++mt) {
                acc[mt][nt] = __builtin_amdgcn_mfma_f32_16x16x32_f16(aH[mt][ks], bH[ks], acc[mt][nt], 0, 0, 0);
                acc[mt][nt] = __builtin_amdgcn_mfma_f32_16x16x32_f16(aH[mt][ks], bL[ks], acc[mt][nt], 0, 0, 0);
                acc[mt][nt] = __builtin_amdgcn_mfma_f32_16x16x32_f16(aL[mt][ks], bH[ks], acc[mt][nt], 0, 0, 0);
            }
    }

#pragma unroll
    for (int mt = 0; mt < 2; ++mt)
#pragma unroll
        for (int nt = 0; nt < 6; ++nt)
#pragma unroll
            for (int r = 0; r < 4; ++r)
                y[(rbase + wave * 32 + mt * 16 + lk * 4 + r) * T_ + nt * 16 + lr] = acc[mt][nt][r];

    // ---- Bp pack: wave owns col-tiles wave*2 + {0,1} of this block ----
#pragma unroll
    for (int ctl = 0; ctl < 2; ++ctl) {
        const int lct = wave * 2 + ctl;                 // 0..7
        const size_t gct = rbase / 16 + lct;            // global col-tile
#pragma unroll
        for (int ks = 0; ks < 3; ++ks) {
            const float* p = &xs[lct * 16 + lr][ks * 32 + lk * 8];
            float4v v0 = *(const float4v*)p;
            float4v v1 = *(const float4v*)(p + 4);
            half8 h, l;
#pragma unroll
            for (int j = 0; j < 4; ++j) {
                f16 h0 = (f16)v0[j]; h[j] = h0; l[j] = (f16)(v0[j] - (float)h0);
                f16 h1 = (f16)v1[j]; h[4 + j] = h1; l[4 + j] = (f16)(v1[j] - (float)h1);
            }
            f16* ob = bp + ((gct * 3 + ks) * 2) * 512 + (size_t)lane * 8;
            *(half8*)ob = h;
            *(half8*)(ob + 512) = l;
        }
    }
}

// ---------------------------------------------------------------------------
// k_attn: persistent, fully unrolled. Block j: xcd = j&7, rank = j>>3;
// iter i: lb = xcd*128 + i*32 + rank (all 32 blocks of an XCD sweep the SAME
// batch -> 786KB Bp resident in that XCD's L2).
// ---------------------------------------------------------------------------
__global__ __launch_bounds__(512, 2) void k_attn(
        const f16* __restrict__ bp, const float* __restrict__ y,
        float* __restrict__ out) {
    __shared__ float ot[32][1028];    // 131.6 KB transpose buffer
    __shared__ float red[8][32];
    __shared__ float stat[32];

    const int tid  = (int)threadIdx.x;
    const int lane = tid & 63;
    const int wave = tid >> 6;
    const int lr = lane & 15;
    const int lk = lane >> 4;
    const int xcd  = (int)blockIdx.x & 7;
    const int rank = (int)blockIdx.x >> 3;

    half8 aH[2][3], aL[2][3];
    float4v b0[6], b1[6];
    float4v acc[2][16];

    // A loader: y rows (fp32, pre-scaled) split on the fly (NT read-once)
    auto loadA = [&](int lb) {
        const int bb = lb >> 6;
        const int r0 = (lb & 63) << 5;
#pragma unroll
        for (int mt = 0; mt < 2; ++mt)
#pragma unroll
            for (int ks = 0; ks < 3; ++ks) {
                const float* p = y + ((size_t)bb * N_ + r0 + mt * 16 + lr) * T_ + ks * 32 + lk * 8;
                float4v v0 = __builtin_nontemporal_load((const float4v*)p);
                float4v v1 = __builtin_nontemporal_load((const float4v*)p + 1);
                half8 h, l;
#pragma unroll
                for (int j = 0; j < 4; ++j) {
                    f16 h0 = (f16)v0[j]; h[j] = h0; l[j] = (f16)(v0[j] - (float)h0);
                    f16 h1 = (f16)v1[j]; h[4 + j] = h1; l[4 + j] = (f16)(v1[j] - (float)h1);
                }
                aH[mt][ks] = h;
                aL[mt][ks] = l;
            }
    };

    // col-tile index (group-contiguous for the transpose epilogue).
    // NOTE: TIDX already contains the wave offset - gb must NOT re-add it.
#define TIDX(c) (((c) & 8 ? 64 : 0) + (wave << 3) + ((c) & 7))
#define ISSUE(gptr, ti, dst)                                                  \
    {                                                                         \
        _Pragma("unroll")                                                     \
        for (int f = 0; f < 6; ++f) {                                         \
            const f16* g = (gptr) + (size_t)(ti) * 3072 + f * 512;            \
            asm volatile("global_load_dwordx4 %0, %1, off"                    \
                         : "=&v"(dst[f]) : "v"(g));                           \
        }                                                                     \
    }

    int lb = xcd * 128 + rank;   // iter 0 row-block
    loadA(lb);
    const f16* gb = bp + ((size_t)(lb >> 6)) * 128 * 6 * 512 + (size_t)lane * 8;
    ISSUE(gb, TIDX(0), b0);
    ISSUE(gb, TIDX(1), b1);
    __builtin_amdgcn_sched_barrier(0);

#pragma unroll
    for (int it = 0; it < 4; ++it) {
        const int b_   = lb >> 6;
        const int row0 = (lb & 63) << 5;
        const size_t obase = (size_t)b_ * N_ * N_;

#pragma unroll
        for (int mt = 0; mt < 2; ++mt)
#pragma unroll
            for (int c = 0; c < 16; ++c) {
                float4v z = {0.f, 0.f, 0.f, 0.f};
                acc[mt][c] = z;
            }

        // ---- main loop (R8 pattern) ----
#pragma unroll
        for (int c = 0; c < 16; ++c) {
            if (c < 15) asm volatile("s_waitcnt vmcnt(6)" ::: "memory");
            else        asm volatile("s_waitcnt vmcnt(0)" ::: "memory");
            __builtin_amdgcn_sched_barrier(0);

            __builtin_amdgcn_s_setprio(1);
            if ((c & 1) == 0) {
#pragma unroll
                for (int ks = 0; ks < 3; ++ks) {
                    acc[0][c] = __builtin_amdgcn_mfma_f32_16x16x32_f16(aH[0][ks], as_h8(b0[ks * 2]),     acc[0][c], 0, 0, 0);
                    acc[1][c] = __builtin_amdgcn_mfma_f32_16x16x32_f16(aH[1][ks], as_h8(b0[ks * 2]),     acc[1][c], 0, 0, 0);
                    acc[0][c] = __builtin_amdgcn_mfma_f32_16x16x32_f16(aH[0][ks], as_h8(b0[ks * 2 + 1]), acc[0][c], 0, 0, 0);
                    acc[1][c] = __builtin_amdgcn_mfma_f32_16x16x32_f16(aH[1][ks], as_h8(b0[ks * 2 + 1]), acc[1][c], 0, 0, 0);
                    acc[0][c] = __builtin_amdgcn_mfma_f32_16x16x32_f16(aL[0][ks], as_h8(b0[ks * 2]),     acc[0][c], 0, 0, 0);
                    acc[1][c] = __builtin_amdgcn_mfma_f32_16x16x32_f16(aL[1][ks], as_h8(b0[ks * 2]),     acc[1][c], 0, 0, 0);
                }
                __builtin_amdgcn_s_setprio(0);
                __builtin_amdgcn_sched_barrier(0);
                if (c + 2 < 16) ISSUE(gb, TIDX(c + 2), b0);
            } else {
#pragma unroll
                for (int ks = 0; ks < 3; ++ks) {
                    acc[0][c] = __builtin_amdgcn_mfma_f32_16x16x32_f16(aH[0][ks], as_h8(b1[ks * 2]),     acc[0][c], 0, 0, 0);
                    acc[1][c] = __builtin_amdgcn_mfma_f32_16x16x32_f16(aH[1][ks], as_h8(b1[ks * 2]),     acc[1][c], 0, 0, 0);
                    acc[0][c] = __builtin_amdgcn_mfma_f32_16x16x32_f16(aH[0][ks], as_h8(b1[ks * 2 + 1]), acc[0][c], 0, 0, 0);
                    acc[1][c] = __builtin_amdgcn_mfma_f32_16x16x32_f16(aH[1][ks], as_h8(b1[ks * 2 + 1]), acc[1][c], 0, 0, 0);
                    acc[0][c] = __builtin_amdgcn_mfma_f32_16x16x32_f16(aL[0][ks], as_h8(b1[ks * 2]),     acc[0][c], 0, 0, 0);
                    acc[1][c] = __builtin_amdgcn_mfma_f32_16x16x32_f16(aL[1][ks], as_h8(b1[ks * 2]),     acc[1][c], 0, 0, 0);
                }
                __builtin_amdgcn_s_setprio(0);
                __builtin_amdgcn_sched_barrier(0);
                if (c + 2 < 16) ISSUE(gb, TIDX(c + 2), b1);
            }
            __builtin_amdgcn_sched_barrier(0);
        }

        // ---- relu (scale folded into Ms), row max ----
        float rmax[2][4];
#pragma unroll
        for (int mt = 0; mt < 2; ++mt)
#pragma unroll
            for (int r = 0; r < 4; ++r) rmax[mt][r] = 0.0f;
#pragma unroll
        for (int mt = 0; mt < 2; ++mt)
#pragma unroll
            for (int c = 0; c < 16; ++c)
#pragma unroll
                for (int r = 0; r < 4; ++r) {
                    float v = fmaxf(acc[mt][c][r], 0.0f);
                    acc[mt][c][r] = v;
                    rmax[mt][r] = fmaxf(rmax[mt][r], v);
                }
#pragma unroll
        for (int mt = 0; mt < 2; ++mt)
#pragma unroll
            for (int r = 0; r < 4; ++r) {
                float m = rmax[mt][r];
                m = fmaxf(m, __shfl_xor(m, 1));
                m = fmaxf(m, __shfl_xor(m, 2));
                m = fmaxf(m, __shfl_xor(m, 4));
                m = fmaxf(m, __shfl_xor(m, 8));
                rmax[mt][r] = m;
            }
        __syncthreads();   // ot/red safe from previous iter
        if (lr == 0) {
#pragma unroll
            for (int mt = 0; mt < 2; ++mt)
#pragma unroll
                for (int r = 0; r < 4; ++r)
                    red[wave][mt * 16 + lk * 4 + r] = rmax[mt][r];
        }
        __syncthreads();
        if (tid < 32) {
            float m = red[0][tid];
#pragma unroll
            for (int w = 1; w < 8; ++w) m = fmaxf(m, red[w][tid]);
            stat[tid] = m;
        }
        __syncthreads();

        float rowm[2][4], rsum[2][4];
#pragma unroll
        for (int mt = 0; mt < 2; ++mt)
#pragma unroll
            for (int r = 0; r < 4; ++r) {
                rowm[mt][r] = stat[mt * 16 + lk * 4 + r];
                rsum[mt][r] = 0.0f;
            }

        // ---- exp, row sum ----
#pragma unroll
        for (int mt = 0; mt < 2; ++mt)
#pragma unroll
            for (int c = 0; c < 16; ++c)
#pragma unroll
                for (int r = 0; r < 4; ++r) {
                    float e = __expf(acc[mt][c][r] - rowm[mt][r]);
                    acc[mt][c][r] = e;
                    rsum[mt][r] += e;
                }
#pragma unroll
        for (int mt = 0; mt < 2; ++mt)
#pragma unroll
            for (int r = 0; r < 4; ++r) {
                float s = rsum[mt][r];
                s += __shfl_xor(s, 1);
                s += __shfl_xor(s, 2);
                s += __shfl_xor(s, 4);
                s += __shfl_xor(s, 8);
                rsum[mt][r] = s;
            }
        __syncthreads();
        if (lr == 0) {
#pragma unroll
            for (int mt = 0; mt < 2; ++mt)
#pragma unroll
                for (int r = 0; r < 4; ++r)
                    red[wave][mt * 16 + lk * 4 + r] = rsum[mt][r];
        }
        __syncthreads();
        if (tid < 32) {
            float s = 0.0f;
#pragma unroll
            for (int w = 0; w < 8; ++w) s += red[w][tid];
            stat[tid] = s;
        }
        __syncthreads();

        float inv[2][4];
#pragma unroll
        for (int mt = 0; mt < 2; ++mt)
#pragma unroll
            for (int r = 0; r < 4; ++r)
                inv[mt][r] = 1.0f / stat[mt * 16 + lk * 4 + r];

        // ---- PREFETCH next iter (A + first two B sets) before stores ----
        const int nlb = xcd * 128 + (it + 1) * 32 + rank;
        if (it < 3) {
            loadA(nlb);
            gb = bp + ((size_t)(nlb >> 6)) * 128 * 6 * 512 + (size_t)lane * 8;
            ISSUE(gb, TIDX(0), b0);
            ISSUE(gb, TIDX(1), b1);
        }

        // ---- normalize + LDS transpose + row-contiguous burst stores ----
#pragma unroll
        for (int g = 0; g < 2; ++g) {
            if (g) __syncthreads();   // protect ot reuse between groups
#pragma unroll
            for (int cc = 0; cc < 8; ++cc) {
                const int c = g * 8 + cc;
#pragma unroll
                for (int mt = 0; mt < 2; ++mt)
#pragma unroll
                    for (int r = 0; r < 4; ++r)
                        ot[mt * 16 + lk * 4 + r][(wave << 7) + cc * 16 + lr] =
                            acc[mt][c][r] * inv[mt][r];
            }
            __syncthreads();
            // each wave writes 4 full rows of this 1024-col group: 1KB bursts
#pragma unroll
            for (int rr = 0; rr < 4; ++rr) {
                const int row = (wave << 2) + rr;
                float* dstp = out + obase + (size_t)(row0 + row) * N_ + g * 1024;
#pragma unroll
                for (int i = 0; i < 4; ++i) {
                    float4v v = *(const float4v*)&ot[row][i * 256 + lane * 4];
                    *(float4v*)(dstp + i * 256 + lane * 4) = v;
                }
            }
        }

        lb = nlb;
    }
#undef ISSUE
#undef TIDX
}

// ---------------------------------------------------------------------------
extern "C" void kernel_launch(void* const* d_in, const int* in_sizes, int n_in,
                              void* d_out, int out_size, void* d_ws, size_t ws_size,
                              hipStream_t stream) {
    const float* x  = (const float*)d_in[0];
    const float* WQ = (const float*)d_in[1];
    const float* WK = (const float*)d_in[2];
    float* out = (float*)d_out;

    char* ws = (char*)d_ws;
    size_t off = 0;
    auto carve = [&](size_t bytes) -> char* {
        char* p = ws + off;
        off += (bytes + 255) & ~(size_t)255;
        return p;
    };
    f16*   mth = (f16*)carve((size_t)T_ * T_ * 2);
    f16*   mtl = (f16*)carve((size_t)T_ * T_ * 2);
    f16*   bpk = (f16*)carve((size_t)B_ * N_ * T_ * 2 * 2);   // 25.2 MB
    float* yw  = (float*)carve((size_t)B_ * N_ * T_ * 4);     // 12.6 MB
    (void)ws_size; (void)in_sizes; (void)n_in; (void)out_size;

    k_m<<<(T_ * T_ + 255) / 256, 256, 0, stream>>>(WQ, WK, mth, mtl);
    k_fuse<<<(B_ * N_) / 128, 256, 0, stream>>>(x, mth, mtl, yw, bpk);
    k_attn<<<256, 512, 0, stream>>>(bpk, yw, out);
}

// Round 16
// 124.360 us; speedup vs baseline: 1.0579x; 1.0235x over previous
//
#include <hip/hip_runtime.h>
#include <hip/hip_bf16.h>

// Variable_Attention: out = softmax(relu((x@WQ)(x@WK)^T)/sqrt(128), axis=-1)
// B=16, N=2048, T=96, D=128. fp32 in/out.
//
// QK^T*c = x Ms x^T with Ms = (WQ WK^T)*c, c = log2(e)/sqrt(128) (exact fp32
// fold; softmax computed base-2 via v_exp_f32 = 2^x). Pipeline:
//   k_m    : Ms^T -> fp16 hi/lo split
//   k_fuse : reads x once (LDS-staged); emits y = x@Ms (fp32) and Bp = x
//            split fp16 hi/lo in MFMA B-fragment stream order (1KB frags)
//   k_attn : R8 structure (proven): 1024 blocks, 32 rows x 2048 cols each,
//            asm depth-2 pipelined B loads (vmcnt(6)), LDS-transpose +
//            row-contiguous 1KB burst stores.
//            Banked from R14/R15 (numerically verified, race-free subset):
//            exp2-fold + relu-deferred epilogue (one fewer acc pass),
//            1028 pad, lgkm-only barriers in the store epilogue.
//            Deferred-store pipeline ABANDONED (2x replay races).
// Workspace: ~38 MB.

typedef _Float16 f16;
typedef _Float16 half8 __attribute__((ext_vector_type(8)));
typedef float float4v __attribute__((ext_vector_type(4)));

#define B_ 16
#define N_ 2048
#define T_ 96
#define D_ 128

static __device__ __forceinline__ half8 as_h8(float4v v) {
    union { float4v f; half8 h; } u; u.f = v; return u.h;
}

// lgkm-only barrier: orders LDS, leaves global stores in flight.
static __device__ __forceinline__ void barx() {
    asm volatile("s_waitcnt lgkmcnt(0)" ::: "memory");
    __builtin_amdgcn_s_barrier();
    __builtin_amdgcn_sched_barrier(0);
}

// ---------------------------------------------------------------------------
// k_m: Ms[t][t2] = (sum_d WQ[t,d]*WK[t2,d]) * log2e/sqrt(128), ^T + split.
// ---------------------------------------------------------------------------
__global__ void k_m(const float* __restrict__ WQ, const float* __restrict__ WK,
                    f16* __restrict__ mth, f16* __restrict__ mtl) {
    int i = blockIdx.x * 256 + threadIdx.x;
    if (i >= T_ * T_) return;
    int t = i / T_, t2 = i % T_;
    const float4v* q = (const float4v*)(WQ + (size_t)t * D_);
    const float4v* k = (const float4v*)(WK + (size_t)t2 * D_);
    float s = 0.0f;
#pragma unroll
    for (int d = 0; d < D_ / 4; ++d) {
        float4v a = q[d], b = k[d];
        s += a[0] * b[0] + a[1] * b[1] + a[2] * b[2] + a[3] * b[3];
    }
    s *= 0.088388347648318447f * 1.4426950408889634f;  // 1/sqrt(128)*log2(e)
    f16 h = (f16)s;
    mth[t2 * T_ + t] = h;
    mtl[t2 * T_ + t] = (f16)(s - (float)h);
}

// ---------------------------------------------------------------------------
// k_fuse: per block, 128 x-rows staged in LDS; (a) y = x@Ms (wave owns 32
// rows), (b) Bp pack (wave owns 2 col-tiles): frag[gct][ks][hl] = 1KB.
// ---------------------------------------------------------------------------
__global__ __launch_bounds__(256) void k_fuse(
        const float* __restrict__ x,
        const f16* __restrict__ mth, const f16* __restrict__ mtl,
        float* __restrict__ y, f16* __restrict__ bp) {
    __shared__ float xs[128][100];

    const int tid  = (int)threadIdx.x;
    const int lane = tid & 63;
    const int wave = tid >> 6;
    const int lr = lane & 15;
    const int lk = lane >> 4;
    const size_t rbase = (size_t)blockIdx.x * 128;

    const float4v* xg = (const float4v*)(x + rbase * T_);
#pragma unroll
    for (int i = 0; i < 12; ++i) {
        int j = i * 256 + tid;
        int row = j / 24, c4 = j % 24;
        float4v v = xg[j];
        *(float4v*)&xs[row][c4 * 4] = v;
    }
    __syncthreads();

    half8 aH[2][3], aL[2][3];
#pragma unroll
    for (int mt = 0; mt < 2; ++mt)
#pragma unroll
        for (int ks = 0; ks < 3; ++ks) {
            const float* p = &xs[wave * 32 + mt * 16 + lr][ks * 32 + lk * 8];
            float4v v0 = *(const float4v*)p;
            float4v v1 = *(const float4v*)(p + 4);
            half8 h, l;
#pragma unroll
            for (int j = 0; j < 4; ++j) {
                f16 h0 = (f16)v0[j]; h[j] = h0; l[j] = (f16)(v0[j] - (float)h0);
                f16 h1 = (f16)v1[j]; h[4 + j] = h1; l[4 + j] = (f16)(v1[j] - (float)h1);
            }
            aH[mt][ks] = h;
            aL[mt][ks] = l;
        }

    float4v acc[2][6];
#pragma unroll
    for (int mt = 0; mt < 2; ++mt)
#pragma unroll
        for (int nt = 0; nt < 6; ++nt) {
            float4v z = {0.f, 0.f, 0.f, 0.f};
            acc[mt][nt] = z;
        }

#pragma unroll
    for (int nt = 0; nt < 6; ++nt) {
        half8 bH[3], bL[3];
#pragma unroll
        for (int ks = 0; ks < 3; ++ks) {
            size_t off = (size_t)(nt * 16 + lr) * T_ + ks * 32 + lk * 8;
            bH[ks] = *(const half8*)(mth + off);
            bL[ks] = *(const half8*)(mtl + off);
        }
#pragma unroll
        for (int ks = 0; ks < 3; ++ks)
#pragma unroll
            for (int mt = 0; mt < 2; ++mt) {
                acc[mt][nt] = __builtin_amdgcn_mfma_f32_16x16x32_f16(aH[mt][ks], bH[ks], acc[mt][nt], 0, 0, 0);
                acc[mt][nt] = __builtin_amdgcn_mfma_f32_16x16x32_f16(aH[mt][ks], bL[ks], acc[mt][nt], 0, 0, 0);
                acc[mt][nt] = __builtin_amdgcn_mfma_f32_16x16x32_f16(aL[mt][ks], bH[ks], acc[mt][nt], 0, 0, 0);
            }
    }

#pragma unroll
    for (int mt = 0; mt < 2; ++mt)
#pragma unroll
        for (int nt = 0; nt < 6; ++nt)
#pragma unroll
            for (int r = 0; r < 4; ++r)
                y[(rbase + wave * 32 + mt * 16 + lk * 4 + r) * T_ + nt * 16 + lr] = acc[mt][nt][r];

#pragma unroll
    for (int ctl = 0; ctl < 2; ++ctl) {
        const int lct = wave * 2 + ctl;
        const size_t gct = rbase / 16 + lct;
#pragma unroll
        for (int ks = 0; ks < 3; ++ks) {
            const float* p = &xs[lct * 16 + lr][ks * 32 + lk * 8];
            float4v v0 = *(const float4v*)p;
            float4v v1 = *(const float4v*)(p + 4);
            half8 h, l;
#pragma unroll
            for (int j = 0; j < 4; ++j) {
                f16 h0 = (f16)v0[j]; h[j] = h0; l[j] = (f16)(v0[j] - (float)h0);
                f16 h1 = (f16)v1[j]; h[4 + j] = h1; l[4 + j] = (f16)(v1[j] - (float)h1);
            }
            f16* ob = bp + ((gct * 3 + ks) * 2) * 512 + (size_t)lane * 8;
            *(half8*)ob = h;
            *(half8*)(ob + 512) = l;
        }
    }
}

// ---------------------------------------------------------------------------
// k_attn: S = y @ x^T fused relu/softmax (R8 structure). 32 rows x 2048 cols
// per block. Wave w owns cols [w*128,+128) of group0 and [1024+w*128,+128) of
// group1. Epilogue: LDS transpose (32x1028) + full-row 1KB burst stores.
// ---------------------------------------------------------------------------
__global__ __launch_bounds__(512, 2) void k_attn(
        const f16* __restrict__ bp, const float* __restrict__ y,
        float* __restrict__ out) {
    __shared__ float ot[32][1028];
    __shared__ float red[8][32];
    __shared__ float stat[32];

    const int tid  = (int)threadIdx.x;
    const int lane = tid & 63;
    const int wave = tid >> 6;
    const int lr = lane & 15;
    const int lk = lane >> 4;

    // XCD-aware bijective swizzle (1024 blocks)
    const int lb   = ((int)blockIdx.x & 7) * 128 + ((int)blockIdx.x >> 3);
    const int b    = lb >> 6;
    const int row0 = (lb & 63) << 5;
    const size_t obase = (size_t)b * N_ * N_;

    // ---- A: y rows (fp32, pre-folded scale) split on the fly (NT reads) ----
    half8 aH[2][3], aL[2][3];
#pragma unroll
    for (int mt = 0; mt < 2; ++mt)
#pragma unroll
        for (int ks = 0; ks < 3; ++ks) {
            const float* p = y + ((size_t)b * N_ + row0 + mt * 16 + lr) * T_ + ks * 32 + lk * 8;
            float4v v0 = __builtin_nontemporal_load((const float4v*)p);
            float4v v1 = __builtin_nontemporal_load((const float4v*)p + 1);
            half8 h, l;
#pragma unroll
            for (int j = 0; j < 4; ++j) {
                f16 h0 = (f16)v0[j]; h[j] = h0; l[j] = (f16)(v0[j] - (float)h0);
                f16 h1 = (f16)v1[j]; h[4 + j] = h1; l[4 + j] = (f16)(v1[j] - (float)h1);
            }
            aH[mt][ks] = h;
            aL[mt][ks] = l;
        }

    float4v acc[2][16];
#pragma unroll
    for (int mt = 0; mt < 2; ++mt)
#pragma unroll
        for (int c = 0; c < 16; ++c) {
            float4v z = {0.f, 0.f, 0.f, 0.f};
            acc[mt][c] = z;
        }

    // col-tile index for loop index c (group-contiguous mapping):
    //   c<8 : tile = wave*8 + c         ; c>=8: tile = 64 + wave*8 + (c-8)
#define TIDX(c) (((c) & 8 ? 64 : 0) + (wave << 3) + ((c) & 7))

    const f16* gb = bp + ((size_t)b * 128 * 6) * 512 + (size_t)lane * 8;

    float4v b0[6], b1[6];
#define ISSUE(ti, dst)                                                        \
    {                                                                         \
        _Pragma("unroll")                                                     \
        for (int f = 0; f < 6; ++f) {                                         \
            const f16* g = gb + (size_t)(ti) * 3072 + f * 512;                \
            asm volatile("global_load_dwordx4 %0, %1, off"                    \
                         : "=&v"(dst[f]) : "v"(g));                           \
        }                                                                     \
    }

    ISSUE(TIDX(0), b0);
    ISSUE(TIDX(1), b1);
    __builtin_amdgcn_sched_barrier(0);

#pragma unroll
    for (int c = 0; c < 16; ++c) {
        if (c < 15) asm volatile("s_waitcnt vmcnt(6)" ::: "memory");
        else        asm volatile("s_waitcnt vmcnt(0)" ::: "memory");
        __builtin_amdgcn_sched_barrier(0);

        __builtin_amdgcn_s_setprio(1);
        if ((c & 1) == 0) {
#pragma unroll
            for (int ks = 0; ks < 3; ++ks) {
                acc[0][c] = __builtin_amdgcn_mfma_f32_16x16x32_f16(aH[0][ks], as_h8(b0[ks * 2]),     acc[0][c], 0, 0, 0);
                acc[1][c] = __builtin_amdgcn_mfma_f32_16x16x32_f16(aH[1][ks], as_h8(b0[ks * 2]),     acc[1][c], 0, 0, 0);
                acc[0][c] = __builtin_amdgcn_mfma_f32_16x16x32_f16(aH[0][ks], as_h8(b0[ks * 2 + 1]), acc[0][c], 0, 0, 0);
                acc[1][c] = __builtin_amdgcn_mfma_f32_16x16x32_f16(aH[1][ks], as_h8(b0[ks * 2 + 1]), acc[1][c], 0, 0, 0);
                acc[0][c] = __builtin_amdgcn_mfma_f32_16x16x32_f16(aL[0][ks], as_h8(b0[ks * 2]),     acc[0][c], 0, 0, 0);
                acc[1][c] = __builtin_amdgcn_mfma_f32_16x16x32_f16(aL[1][ks], as_h8(b0[ks * 2]),     acc[1][c], 0, 0, 0);
            }
            __builtin_amdgcn_s_setprio(0);
            __builtin_amdgcn_sched_barrier(0);
            if (c + 2 < 16) ISSUE(TIDX(c + 2), b0);
        } else {
#pragma unroll
            for (int ks = 0; ks < 3; ++ks) {
                acc[0][c] = __builtin_amdgcn_mfma_f32_16x16x32_f16(aH[0][ks], as_h8(b1[ks * 2]),     acc[0][c], 0, 0, 0);
                acc[1][c] = __builtin_amdgcn_mfma_f32_16x16x32_f16(aH[1][ks], as_h8(b1[ks * 2]),     acc[1][c], 0, 0, 0);
                acc[0][c] = __builtin_amdgcn_mfma_f32_16x16x32_f16(aH[0][ks], as_h8(b1[ks * 2 + 1]), acc[0][c], 0, 0, 0);
                acc[1][c] = __builtin_amdgcn_mfma_f32_16x16x32_f16(aH[1][ks], as_h8(b1[ks * 2 + 1]), acc[1][c], 0, 0, 0);
                acc[0][c] = __builtin_amdgcn_mfma_f32_16x16x32_f16(aL[0][ks], as_h8(b1[ks * 2]),     acc[0][c], 0, 0, 0);
                acc[1][c] = __builtin_amdgcn_mfma_f32_16x16x32_f16(aL[1][ks], as_h8(b1[ks * 2]),     acc[1][c], 0, 0, 0);
            }
            __builtin_amdgcn_s_setprio(0);
            __builtin_amdgcn_sched_barrier(0);
            if (c + 2 < 16) ISSUE(TIDX(c + 2), b1);
        }
        __builtin_amdgcn_sched_barrier(0);
    }
#undef ISSUE
#undef TIDX

    // ---- row max over RAW acc (relu deferred into exp pass) ----
    float rmax[2][4];
#pragma unroll
    for (int mt = 0; mt < 2; ++mt)
#pragma unroll
        for (int r = 0; r < 4; ++r) rmax[mt][r] = -3.4e38f;
#pragma unroll
    for (int mt = 0; mt < 2; ++mt)
#pragma unroll
        for (int c = 0; c < 16; ++c)
#pragma unroll
            for (int r = 0; r < 4; ++r)
                rmax[mt][r] = fmaxf(rmax[mt][r], acc[mt][c][r]);
#pragma unroll
    for (int mt = 0; mt < 2; ++mt)
#pragma unroll
        for (int r = 0; r < 4; ++r) {
            float m = rmax[mt][r];
            m = fmaxf(m, __shfl_xor(m, 1));
            m = fmaxf(m, __shfl_xor(m, 2));
            m = fmaxf(m, __shfl_xor(m, 4));
            m = fmaxf(m, __shfl_xor(m, 8));
            rmax[mt][r] = m;
        }
    if (lr == 0) {
#pragma unroll
        for (int mt = 0; mt < 2; ++mt)
#pragma unroll
            for (int r = 0; r < 4; ++r)
                red[wave][mt * 16 + lk * 4 + r] = rmax[mt][r];
    }
    __syncthreads();
    if (tid < 32) {
        float m = red[0][tid];
#pragma unroll
        for (int w = 1; w < 8; ++w) m = fmaxf(m, red[w][tid]);
        stat[tid] = m;
    }
    __syncthreads();

    float rowm[2][4], rsum[2][4];
#pragma unroll
    for (int mt = 0; mt < 2; ++mt)
#pragma unroll
        for (int r = 0; r < 4; ++r) {
            rowm[mt][r] = fmaxf(stat[mt * 16 + lk * 4 + r], 0.0f);
            rsum[mt][r] = 0.0f;
        }

    // ---- exp (base-2, scale pre-folded) + relu + row sum ----
#pragma unroll
    for (int mt = 0; mt < 2; ++mt)
#pragma unroll
        for (int c = 0; c < 16; ++c)
#pragma unroll
            for (int r = 0; r < 4; ++r) {
                float xv = fmaxf(acc[mt][c][r], 0.0f) - rowm[mt][r];
                float e;
                asm("v_exp_f32 %0, %1" : "=v"(e) : "v"(xv));
                acc[mt][c][r] = e;
                rsum[mt][r] += e;
            }
#pragma unroll
    for (int mt = 0; mt < 2; ++mt)
#pragma unroll
        for (int r = 0; r < 4; ++r) {
            float s = rsum[mt][r];
            s += __shfl_xor(s, 1);
            s += __shfl_xor(s, 2);
            s += __shfl_xor(s, 4);
            s += __shfl_xor(s, 8);
            rsum[mt][r] = s;
        }
    __syncthreads();
    if (lr == 0) {
#pragma unroll
        for (int mt = 0; mt < 2; ++mt)
#pragma unroll
            for (int r = 0; r < 4; ++r)
                red[wave][mt * 16 + lk * 4 + r] = rsum[mt][r];
    }
    __syncthreads();
    if (tid < 32) {
        float s = 0.0f;
#pragma unroll
        for (int w = 0; w < 8; ++w) s += red[w][tid];
        stat[tid] = s;
    }
    __syncthreads();

    float inv[2][4];
#pragma unroll
    for (int mt = 0; mt < 2; ++mt)
#pragma unroll
        for (int r = 0; r < 4; ++r)
            inv[mt][r] = 1.0f / stat[mt * 16 + lk * 4 + r];

    // ---- normalize + LDS transpose + row-contiguous burst stores ----
    // barx (lgkm-only) here: these barriers only order LDS; global stores
    // may stay in flight (no vmcnt(0) drain per group).
#pragma unroll
    for (int g = 0; g < 2; ++g) {
        if (g) barx();   // protect ot reuse between groups
#pragma unroll
        for (int cc = 0; cc < 8; ++cc) {
            const int c = g * 8 + cc;
#pragma unroll
            for (int mt = 0; mt < 2; ++mt)
#pragma unroll
                for (int r = 0; r < 4; ++r)
                    ot[mt * 16 + lk * 4 + r][(wave << 7) + cc * 16 + lr] =
                        acc[mt][c][r] * inv[mt][r];
        }
        barx();
        // each wave writes 4 full rows of this 1024-col group: 1KB bursts
#pragma unroll
        for (int rr = 0; rr < 4; ++rr) {
            const int row = (wave << 2) + rr;
            float* dstp = out + obase + (size_t)(row0 + row) * N_ + g * 1024;
#pragma unroll
            for (int i = 0; i < 4; ++i) {
                float4v v = *(const float4v*)&ot[row][i * 256 + lane * 4];
                *(float4v*)(dstp + i * 256 + lane * 4) = v;
            }
        }
    }
}

// ---------------------------------------------------------------------------
extern "C" void kernel_launch(void* const* d_in, const int* in_sizes, int n_in,
                              void* d_out, int out_size, void* d_ws, size_t ws_size,
                              hipStream_t stream) {
    const float* x  = (const float*)d_in[0];
    const float* WQ = (const float*)d_in[1];
    const float* WK = (const float*)d_in[2];
    float* out = (float*)d_out;

    char* ws = (char*)d_ws;
    size_t off = 0;
    auto carve = [&](size_t bytes) -> char* {
        char* p = ws + off;
        off += (bytes + 255) & ~(size_t)255;
        return p;
    };
    f16*   mth = (f16*)carve((size_t)T_ * T_ * 2);
    f16*   mtl = (f16*)carve((size_t)T_ * T_ * 2);
    f16*   bpk = (f16*)carve((size_t)B_ * N_ * T_ * 2 * 2);   // 25.2 MB
    float* yw  = (float*)carve((size_t)B_ * N_ * T_ * 4);     // 12.6 MB
    (void)ws_size; (void)in_sizes; (void)n_in; (void)out_size;

    k_m<<<(T_ * T_ + 255) / 256, 256, 0, stream>>>(WQ, WK, mth, mtl);
    k_fuse<<<(B_ * N_) / 128, 256, 0, stream>>>(x, mth, mtl, yw, bpk);
    k_attn<<<B_ * (N_ / 32), 512, 0, stream>>>(bpk, yw, out);
}

// Round 18
// 123.890 us; speedup vs baseline: 1.0619x; 1.0038x over previous
//
#include <hip/hip_runtime.h>
#include <hip/hip_bf16.h>

// Variable_Attention: out = softmax(relu((x@WQ)(x@WK)^T)/sqrt(128), axis=-1)
// B=16, N=2048, T=96, D=128. fp32 in/out.
//
// QK^T*c = x Ms x^T with Ms = (WQ WK^T)*c, c = log2(e)/sqrt(128) (exact fp32
// fold; softmax computed base-2 via v_exp_f32 = 2^x). Pipeline:
//   k_m    : Ms^T -> fp16 hi/lo split
//   k_fuse : reads x once (LDS-staged); emits y = x@Ms (fp32) and Bp = x
//            split fp16 hi/lo in MFMA B-fragment stream order (1KB frags)
//   k_attn : R8 structure (proven): 1024 blocks, 32 rows x 2048 cols each,
//            asm depth-2 pipelined B loads (vmcnt(6)), LDS-transpose +
//            row-contiguous 1KB burst stores. exp2-fold + relu-deferred
//            epilogue, 1028 pad, lgkm-only barriers in the store epilogue.
//            Deferred-store pipeline PERMANENTLY ABANDONED (3x replay races
//            R14/R15/R17 - asm-store source-register hazards not locatable
//            without disasm). This is the R16 kernel (124.4 us, verified).
// Workspace: ~38 MB.

typedef _Float16 f16;
typedef _Float16 half8 __attribute__((ext_vector_type(8)));
typedef float float4v __attribute__((ext_vector_type(4)));

#define B_ 16
#define N_ 2048
#define T_ 96
#define D_ 128

static __device__ __forceinline__ half8 as_h8(float4v v) {
    union { float4v f; half8 h; } u; u.f = v; return u.h;
}

// lgkm-only barrier: orders LDS, leaves global stores in flight.
static __device__ __forceinline__ void barx() {
    asm volatile("s_waitcnt lgkmcnt(0)" ::: "memory");
    __builtin_amdgcn_s_barrier();
    __builtin_amdgcn_sched_barrier(0);
}

// ---------------------------------------------------------------------------
// k_m: Ms[t][t2] = (sum_d WQ[t,d]*WK[t2,d]) * log2e/sqrt(128), ^T + split.
// ---------------------------------------------------------------------------
__global__ void k_m(const float* __restrict__ WQ, const float* __restrict__ WK,
                    f16* __restrict__ mth, f16* __restrict__ mtl) {
    int i = blockIdx.x * 256 + threadIdx.x;
    if (i >= T_ * T_) return;
    int t = i / T_, t2 = i % T_;
    const float4v* q = (const float4v*)(WQ + (size_t)t * D_);
    const float4v* k = (const float4v*)(WK + (size_t)t2 * D_);
    float s = 0.0f;
#pragma unroll
    for (int d = 0; d < D_ / 4; ++d) {
        float4v a = q[d], b = k[d];
        s += a[0] * b[0] + a[1] * b[1] + a[2] * b[2] + a[3] * b[3];
    }
    s *= 0.088388347648318447f * 1.4426950408889634f;  // 1/sqrt(128)*log2(e)
    f16 h = (f16)s;
    mth[t2 * T_ + t] = h;
    mtl[t2 * T_ + t] = (f16)(s - (float)h);
}

// ---------------------------------------------------------------------------
// k_fuse: per block, 128 x-rows staged in LDS; (a) y = x@Ms (wave owns 32
// rows), (b) Bp pack (wave owns 2 col-tiles): frag[gct][ks][hl] = 1KB.
// ---------------------------------------------------------------------------
__global__ __launch_bounds__(256) void k_fuse(
        const float* __restrict__ x,
        const f16* __restrict__ mth, const f16* __restrict__ mtl,
        float* __restrict__ y, f16* __restrict__ bp) {
    __shared__ float xs[128][100];

    const int tid  = (int)threadIdx.x;
    const int lane = tid & 63;
    const int wave = tid >> 6;
    const int lr = lane & 15;
    const int lk = lane >> 4;
    const size_t rbase = (size_t)blockIdx.x * 128;

    const float4v* xg = (const float4v*)(x + rbase * T_);
#pragma unroll
    for (int i = 0; i < 12; ++i) {
        int j = i * 256 + tid;
        int row = j / 24, c4 = j % 24;
        float4v v = xg[j];
        *(float4v*)&xs[row][c4 * 4] = v;
    }
    __syncthreads();

    half8 aH[2][3], aL[2][3];
#pragma unroll
    for (int mt = 0; mt < 2; ++mt)
#pragma unroll
        for (int ks = 0; ks < 3; ++ks) {
            const float* p = &xs[wave * 32 + mt * 16 + lr][ks * 32 + lk * 8];
            float4v v0 = *(const float4v*)p;
            float4v v1 = *(const float4v*)(p + 4);
            half8 h, l;
#pragma unroll
            for (int j = 0; j < 4; ++j) {
                f16 h0 = (f16)v0[j]; h[j] = h0; l[j] = (f16)(v0[j] - (float)h0);
                f16 h1 = (f16)v1[j]; h[4 + j] = h1; l[4 + j] = (f16)(v1[j] - (float)h1);
            }
            aH[mt][ks] = h;
            aL[mt][ks] = l;
        }

    float4v acc[2][6];
#pragma unroll
    for (int mt = 0; mt < 2; ++mt)
#pragma unroll
        for (int nt = 0; nt < 6; ++nt) {
            float4v z = {0.f, 0.f, 0.f, 0.f};
            acc[mt][nt] = z;
        }

#pragma unroll
    for (int nt = 0; nt < 6; ++nt) {
        half8 bH[3], bL[3];
#pragma unroll
        for (int ks = 0; ks < 3; ++ks) {
            size_t off = (size_t)(nt * 16 + lr) * T_ + ks * 32 + lk * 8;
            bH[ks] = *(const half8*)(mth + off);
            bL[ks] = *(const half8*)(mtl + off);
        }
#pragma unroll
        for (int ks = 0; ks < 3; ++ks)
#pragma unroll
            for (int mt = 0; mt < 2; ++mt) {
                acc[mt][nt] = __builtin_amdgcn_mfma_f32_16x16x32_f16(aH[mt][ks], bH[ks], acc[mt][nt], 0, 0, 0);
                acc[mt][nt] = __builtin_amdgcn_mfma_f32_16x16x32_f16(aH[mt][ks], bL[ks], acc[mt][nt], 0, 0, 0);
                acc[mt][nt] = __builtin_amdgcn_mfma_f32_16x16x32_f16(aL[mt][ks], bH[ks], acc[mt][nt], 0, 0, 0);
            }
    }

#pragma unroll
    for (int mt = 0; mt < 2; ++mt)
#pragma unroll
        for (int nt = 0; nt < 6; ++nt)
#pragma unroll
            for (int r = 0; r < 4; ++r)
                y[(rbase + wave * 32 + mt * 16 + lk * 4 + r) * T_ + nt * 16 + lr] = acc[mt][nt][r];

#pragma unroll
    for (int ctl = 0; ctl < 2; ++ctl) {
        const int lct = wave * 2 + ctl;
        const size_t gct = rbase / 16 + lct;
#pragma unroll
        for (int ks = 0; ks < 3; ++ks) {
            const float* p = &xs[lct * 16 + lr][ks * 32 + lk * 8];
            float4v v0 = *(const float4v*)p;
            float4v v1 = *(const float4v*)(p + 4);
            half8 h, l;
#pragma unroll
            for (int j = 0; j < 4; ++j) {
                f16 h0 = (f16)v0[j]; h[j] = h0; l[j] = (f16)(v0[j] - (float)h0);
                f16 h1 = (f16)v1[j]; h[4 + j] = h1; l[4 + j] = (f16)(v1[j] - (float)h1);
            }
            f16* ob = bp + ((gct * 3 + ks) * 2) * 512 + (size_t)lane * 8;
            *(half8*)ob = h;
            *(half8*)(ob + 512) = l;
        }
    }
}

// ---------------------------------------------------------------------------
// k_attn: S = y @ x^T fused relu/softmax (R8 structure). 32 rows x 2048 cols
// per block. Wave w owns cols [w*128,+128) of group0 and [1024+w*128,+128) of
// group1. Epilogue: LDS transpose (32x1028) + full-row 1KB burst stores.
// ---------------------------------------------------------------------------
__global__ __launch_bounds__(512, 2) void k_attn(
        const f16* __restrict__ bp, const float* __restrict__ y,
        float* __restrict__ out) {
    __shared__ float ot[32][1028];
    __shared__ float red[8][32];
    __shared__ float stat[32];

    const int tid  = (int)threadIdx.x;
    const int lane = tid & 63;
    const int wave = tid >> 6;
    const int lr = lane & 15;
    const int lk = lane >> 4;

    // XCD-aware bijective swizzle (1024 blocks)
    const int lb   = ((int)blockIdx.x & 7) * 128 + ((int)blockIdx.x >> 3);
    const int b    = lb >> 6;
    const int row0 = (lb & 63) << 5;
    const size_t obase = (size_t)b * N_ * N_;

    // ---- A: y rows (fp32, pre-folded scale) split on the fly (NT reads) ----
    half8 aH[2][3], aL[2][3];
#pragma unroll
    for (int mt = 0; mt < 2; ++mt)
#pragma unroll
        for (int ks = 0; ks < 3; ++ks) {
            const float* p = y + ((size_t)b * N_ + row0 + mt * 16 + lr) * T_ + ks * 32 + lk * 8;
            float4v v0 = __builtin_nontemporal_load((const float4v*)p);
            float4v v1 = __builtin_nontemporal_load((const float4v*)p + 1);
            half8 h, l;
#pragma unroll
            for (int j = 0; j < 4; ++j) {
                f16 h0 = (f16)v0[j]; h[j] = h0; l[j] = (f16)(v0[j] - (float)h0);
                f16 h1 = (f16)v1[j]; h[4 + j] = h1; l[4 + j] = (f16)(v1[j] - (float)h1);
            }
            aH[mt][ks] = h;
            aL[mt][ks] = l;
        }

    float4v acc[2][16];
#pragma unroll
    for (int mt = 0; mt < 2; ++mt)
#pragma unroll
        for (int c = 0; c < 16; ++c) {
            float4v z = {0.f, 0.f, 0.f, 0.f};
            acc[mt][c] = z;
        }

    // col-tile index for loop index c (group-contiguous mapping):
    //   c<8 : tile = wave*8 + c         ; c>=8: tile = 64 + wave*8 + (c-8)
#define TIDX(c) (((c) & 8 ? 64 : 0) + (wave << 3) + ((c) & 7))

    const f16* gb = bp + ((size_t)b * 128 * 6) * 512 + (size_t)lane * 8;

    float4v b0[6], b1[6];
#define ISSUE(ti, dst)                                                        \
    {                                                                         \
        _Pragma("unroll")                                                     \
        for (int f = 0; f < 6; ++f) {                                         \
            const f16* g = gb + (size_t)(ti) * 3072 + f * 512;                \
            asm volatile("global_load_dwordx4 %0, %1, off"                    \
                         : "=&v"(dst[f]) : "v"(g));                           \
        }                                                                     \
    }

    ISSUE(TIDX(0), b0);
    ISSUE(TIDX(1), b1);
    __builtin_amdgcn_sched_barrier(0);

#pragma unroll
    for (int c = 0; c < 16; ++c) {
        if (c < 15) asm volatile("s_waitcnt vmcnt(6)" ::: "memory");
        else        asm volatile("s_waitcnt vmcnt(0)" ::: "memory");
        __builtin_amdgcn_sched_barrier(0);

        __builtin_amdgcn_s_setprio(1);
        if ((c & 1) == 0) {
#pragma unroll
            for (int ks = 0; ks < 3; ++ks) {
                acc[0][c] = __builtin_amdgcn_mfma_f32_16x16x32_f16(aH[0][ks], as_h8(b0[ks * 2]),     acc[0][c], 0, 0, 0);
                acc[1][c] = __builtin_amdgcn_mfma_f32_16x16x32_f16(aH[1][ks], as_h8(b0[ks * 2]),     acc[1][c], 0, 0, 0);
                acc[0][c] = __builtin_amdgcn_mfma_f32_16x16x32_f16(aH[0][ks], as_h8(b0[ks * 2 + 1]), acc[0][c], 0, 0, 0);
                acc[1][c] = __builtin_amdgcn_mfma_f32_16x16x32_f16(aH[1][ks], as_h8(b0[ks * 2 + 1]), acc[1][c], 0, 0, 0);
                acc[0][c] = __builtin_amdgcn_mfma_f32_16x16x32_f16(aL[0][ks], as_h8(b0[ks * 2]),     acc[0][c], 0, 0, 0);
                acc[1][c] = __builtin_amdgcn_mfma_f32_16x16x32_f16(aL[1][ks], as_h8(b0[ks * 2]),     acc[1][c], 0, 0, 0);
            }
            __builtin_amdgcn_s_setprio(0);
            __builtin_amdgcn_sched_barrier(0);
            if (c + 2 < 16) ISSUE(TIDX(c + 2), b0);
        } else {
#pragma unroll
            for (int ks = 0; ks < 3; ++ks) {
                acc[0][c] = __builtin_amdgcn_mfma_f32_16x16x32_f16(aH[0][ks], as_h8(b1[ks * 2]),     acc[0][c], 0, 0, 0);
                acc[1][c] = __builtin_amdgcn_mfma_f32_16x16x32_f16(aH[1][ks], as_h8(b1[ks * 2]),     acc[1][c], 0, 0, 0);
                acc[0][c] = __builtin_amdgcn_mfma_f32_16x16x32_f16(aH[0][ks], as_h8(b1[ks * 2 + 1]), acc[0][c], 0, 0, 0);
                acc[1][c] = __builtin_amdgcn_mfma_f32_16x16x32_f16(aH[1][ks], as_h8(b1[ks * 2 + 1]), acc[1][c], 0, 0, 0);
                acc[0][c] = __builtin_amdgcn_mfma_f32_16x16x32_f16(aL[0][ks], as_h8(b1[ks * 2]),     acc[0][c], 0, 0, 0);
                acc[1][c] = __builtin_amdgcn_mfma_f32_16x16x32_f16(aL[1][ks], as_h8(b1[ks * 2]),     acc[1][c], 0, 0, 0);
            }
            __builtin_amdgcn_s_setprio(0);
            __builtin_amdgcn_sched_barrier(0);
            if (c + 2 < 16) ISSUE(TIDX(c + 2), b1);
        }
        __builtin_amdgcn_sched_barrier(0);
    }
#undef ISSUE
#undef TIDX

    // ---- row max over RAW acc (relu deferred into exp pass) ----
    float rmax[2][4];
#pragma unroll
    for (int mt = 0; mt < 2; ++mt)
#pragma unroll
        for (int r = 0; r < 4; ++r) rmax[mt][r] = -3.4e38f;
#pragma unroll
    for (int mt = 0; mt < 2; ++mt)
#pragma unroll
        for (int c = 0; c < 16; ++c)
#pragma unroll
            for (int r = 0; r < 4; ++r)
                rmax[mt][r] = fmaxf(rmax[mt][r], acc[mt][c][r]);
#pragma unroll
    for (int mt = 0; mt < 2; ++mt)
#pragma unroll
        for (int r = 0; r < 4; ++r) {
            float m = rmax[mt][r];
            m = fmaxf(m, __shfl_xor(m, 1));
            m = fmaxf(m, __shfl_xor(m, 2));
            m = fmaxf(m, __shfl_xor(m, 4));
            m = fmaxf(m, __shfl_xor(m, 8));
            rmax[mt][r] = m;
        }
    if (lr == 0) {
#pragma unroll
        for (int mt = 0; mt < 2; ++mt)
#pragma unroll
            for (int r = 0; r < 4; ++r)
                red[wave][mt * 16 + lk * 4 + r] = rmax[mt][r];
    }
    __syncthreads();
    if (tid < 32) {
        float m = red[0][tid];
#pragma unroll
        for (int w = 1; w < 8; ++w) m = fmaxf(m, red[w][tid]);
        stat[tid] = m;
    }
    __syncthreads();

    float rowm[2][4], rsum[2][4];
#pragma unroll
    for (int mt = 0; mt < 2; ++mt)
#pragma unroll
        for (int r = 0; r < 4; ++r) {
            rowm[mt][r] = fmaxf(stat[mt * 16 + lk * 4 + r], 0.0f);
            rsum[mt][r] = 0.0f;
        }

    // ---- exp (base-2, scale pre-folded) + relu + row sum ----
#pragma unroll
    for (int mt = 0; mt < 2; ++mt)
#pragma unroll
        for (int c = 0; c < 16; ++c)
#pragma unroll
            for (int r = 0; r < 4; ++r) {
                float xv = fmaxf(acc[mt][c][r], 0.0f) - rowm[mt][r];
                float e;
                asm("v_exp_f32 %0, %1" : "=v"(e) : "v"(xv));
                acc[mt][c][r] = e;
                rsum[mt][r] += e;
            }
#pragma unroll
    for (int mt = 0; mt < 2; ++mt)
#pragma unroll
        for (int r = 0; r < 4; ++r) {
            float s = rsum[mt][r];
            s += __shfl_xor(s, 1);
            s += __shfl_xor(s, 2);
            s += __shfl_xor(s, 4);
            s += __shfl_xor(s, 8);
            rsum[mt][r] = s;
        }
    __syncthreads();
    if (lr == 0) {
#pragma unroll
        for (int mt = 0; mt < 2; ++mt)
#pragma unroll
            for (int r = 0; r < 4; ++r)
                red[wave][mt * 16 + lk * 4 + r] = rsum[mt][r];
    }
    __syncthreads();
    if (tid < 32) {
        float s = 0.0f;
#pragma unroll
        for (int w = 0; w < 8; ++w) s += red[w][tid];
        stat[tid] = s;
    }
    __syncthreads();

    float inv[2][4];
#pragma unroll
    for (int mt = 0; mt < 2; ++mt)
#pragma unroll
        for (int r = 0; r < 4; ++r)
            inv[mt][r] = 1.0f / stat[mt * 16 + lk * 4 + r];

    // ---- normalize + LDS transpose + row-contiguous burst stores ----
    // barx (lgkm-only) here: these barriers only order LDS; global stores
    // may stay in flight (no vmcnt(0) drain per group).
#pragma unroll
    for (int g = 0; g < 2; ++g) {
        if (g) barx();   // protect ot reuse between groups
#pragma unroll
        for (int cc = 0; cc < 8; ++cc) {
            const int c = g * 8 + cc;
#pragma unroll
            for (int mt = 0; mt < 2; ++mt)
#pragma unroll
                for (int r = 0; r < 4; ++r)
                    ot[mt * 16 + lk * 4 + r][(wave << 7) + cc * 16 + lr] =
                        acc[mt][c][r] * inv[mt][r];
        }
        barx();
        // each wave writes 4 full rows of this 1024-col group: 1KB bursts
#pragma unroll
        for (int rr = 0; rr < 4; ++rr) {
            const int row = (wave << 2) + rr;
            float* dstp = out + obase + (size_t)(row0 + row) * N_ + g * 1024;
#pragma unroll
            for (int i = 0; i < 4; ++i) {
                float4v v = *(const float4v*)&ot[row][i * 256 + lane * 4];
                *(float4v*)(dstp + i * 256 + lane * 4) = v;
            }
        }
    }
}

// ---------------------------------------------------------------------------
extern "C" void kernel_launch(void* const* d_in, const int* in_sizes, int n_in,
                              void* d_out, int out_size, void* d_ws, size_t ws_size,
                              hipStream_t stream) {
    const float* x  = (const float*)d_in[0];
    const float* WQ = (const float*)d_in[1];
    const float* WK = (const float*)d_in[2];
    float* out = (float*)d_out;

    char* ws = (char*)d_ws;
    size_t off = 0;
    auto carve = [&](size_t bytes) -> char* {
        char* p = ws + off;
        off += (bytes + 255) & ~(size_t)255;
        return p;
    };
    f16*   mth = (f16*)carve((size_t)T_ * T_ * 2);
    f16*   mtl = (f16*)carve((size_t)T_ * T_ * 2);
    f16*   bpk = (f16*)carve((size_t)B_ * N_ * T_ * 2 * 2);   // 25.2 MB
    float* yw  = (float*)carve((size_t)B_ * N_ * T_ * 4);     // 12.6 MB
    (void)ws_size; (void)in_sizes; (void)n_in; (void)out_size;

    k_m<<<(T_ * T_ + 255) / 256, 256, 0, stream>>>(WQ, WK, mth, mtl);
    k_fuse<<<(B_ * N_) / 128, 256, 0, stream>>>(x, mth, mtl, yw, bpk);
    k_attn<<<B_ * (N_ / 32), 512, 0, stream>>>(bpk, yw, out);
}